// Round 9
// baseline (50.665 us; speedup 1.0000x reference)
//
#include <hip/hip_runtime.h>
#include <hip/hip_bf16.h>
#include <math.h>

#define NEG_SLOPE 0.01f

typedef __attribute__((ext_vector_type(8))) short bf16x8;
typedef __attribute__((ext_vector_type(4))) float f32x4;

__device__ __forceinline__ float lrelu(float v) {
    return v > 0.0f ? v : NEG_SLOPE * v;
}

__device__ __forceinline__ short f2bf(float f) {
    __hip_bfloat16 h = __float2bfloat16(f);
    return *reinterpret_cast<short*>(&h);
}

// ---------------------------------------------------------------------------
// Fused kernel 1.
// Blocks [0, SB): node scores via MFMA + bf16 X copy. W1 frags staged into
//   LDS ONCE per block, then a grid-stride loop over 64-node tiles amortizes
//   the staging (tile += SB).
// Blocks [SB, ...): per-edge member offsets from sorted edge_ids.
// ---------------------------------------------------------------------------
__global__ void __launch_bounds__(256) k_score_and_offsets(
    const float* __restrict__ X, const float* __restrict__ W1,
    const float* __restrict__ b1, const float* __restrict__ W2,
    const float* __restrict__ b2, float* __restrict__ sarr,
    unsigned short* __restrict__ Xb, int N, int SB, int NT,
    const int* __restrict__ edge_ids, int* __restrict__ off, int M, int E) {
    __shared__ short w1s[32 * 64 * 8];  // 32 KB frag image of W1

    int b = blockIdx.x;
    int tid = threadIdx.x;

    if (b >= SB) {
        // ---- offsets path (no LDS use) ----
        int m = (b - SB) * 256 + tid;
        if (m >= M) return;
        int e = edge_ids[m];
        if (m == 0) {
            for (int q = 0; q <= e; ++q) off[q] = 0;
        } else {
            int p = edge_ids[m - 1];
            for (int q = p + 1; q <= e; ++q) off[q] = m;
        }
        if (m == M - 1) {
            for (int q = e + 1; q <= E; ++q) off[q] = M;
        }
        return;
    }

    // ---- node-score path ----
    // stage W1 -> LDS in MFMA B-frag layout (frag fc=jt*4+kc, lane, elem e):
    // w1s[(fc*64+lane)*8+e] = bf16(W1[(kc*32+(lane>>4)*8+e)*128 + jt*16+(lane&15)])
#pragma unroll
    for (int it = 0; it < 8; ++it) {
        int t = it * 256 + tid;          // 0..2047 virtual prep thread
        int lane = t & 63;
        int fc = t >> 6;
        int jt = fc >> 2, kc = fc & 3;
        int col = lane & 15;
        int k0 = kc * 32 + ((lane >> 4) << 3);
        const float* wsrc = W1 + (size_t)k0 * 128 + jt * 16 + col;
        bf16x8 fr;
#pragma unroll
        for (int e = 0; e < 8; ++e) fr[e] = f2bf(wsrc[e * 128]);
        *(bf16x8*)(w1s + (size_t)t * 8) = fr;
    }
    __syncthreads();

    int wid = tid >> 6, lane = tid & 63;
    int c15 = lane & 15, g = lane >> 4;

    float b1v[8], w2v[8];
#pragma unroll
    for (int jt = 0; jt < 8; ++jt) {
        b1v[jt] = b1[jt * 16 + c15];
        w2v[jt] = W2[jt * 16 + c15];
    }
    float bb = b2[0];

    for (int tile = b; tile < NT; tile += SB) {
        int n0 = tile * 64 + wid * 16;

        int arow = n0 + c15;
        size_t srow = (size_t)(arow < N ? arow : N - 1);
        const float* xr = X + srow * 128 + g * 8;
        bf16x8 afr[4];
#pragma unroll
        for (int kc = 0; kc < 4; ++kc) {
            float4 f0 = *(const float4*)(xr + kc * 32);
            float4 f1 = *(const float4*)(xr + kc * 32 + 4);
            bf16x8 a;
            a[0] = f2bf(f0.x); a[1] = f2bf(f0.y); a[2] = f2bf(f0.z); a[3] = f2bf(f0.w);
            a[4] = f2bf(f1.x); a[5] = f2bf(f1.y); a[6] = f2bf(f1.z); a[7] = f2bf(f1.w);
            afr[kc] = a;
            if (Xb)
                *(bf16x8*)(Xb + srow * 128 + kc * 32 + g * 8) = a;
        }

        float sv[4] = {0.f, 0.f, 0.f, 0.f};
#pragma unroll
        for (int jt = 0; jt < 8; ++jt) {
            f32x4 acc = {0.f, 0.f, 0.f, 0.f};
#pragma unroll
            for (int kc = 0; kc < 4; ++kc) {
                bf16x8 bfr = *(const bf16x8*)(w1s + ((jt * 4 + kc) * 64 + lane) * 8);
                acc = __builtin_amdgcn_mfma_f32_16x16x32_bf16(afr[kc], bfr, acc, 0, 0, 0);
            }
#pragma unroll
            for (int i = 0; i < 4; ++i) {
                float h = acc[i] + b1v[jt];
                h = h > 0.f ? h : NEG_SLOPE * h;
                sv[i] += h * w2v[jt];
            }
        }

#pragma unroll
        for (int d = 1; d < 16; d <<= 1) {
#pragma unroll
            for (int i = 0; i < 4; ++i) sv[i] += __shfl_xor(sv[i], d, 64);
        }
        if (c15 == 0) {
#pragma unroll
            for (int i = 0; i < 4; ++i) {
                int node = n0 + g * 4 + i;
                if (node < N) sarr[node] = sv[i] + bb;
            }
        }
    }
}

// ---------------------------------------------------------------------------
// 16-rows-per-iteration weighted accumulate: FOUR independent row gathers in
// flight per wave (rows t+g, t+4+g, t+8+g, t+12+g), 16 lanes per row,
// 8 cols per lane. prw is zero-padded (beta=0, idx=0) so loop is branch-free.
// ---------------------------------------------------------------------------
template <int BF>
__device__ __forceinline__ void row16_acc(const float2* __restrict__ prw, int t,
                                          int g, int c,
                                          const unsigned short* __restrict__ Xb,
                                          const float* __restrict__ X,
                                          float* __restrict__ acc) {
    float2 p0 = prw[t + g];
    float2 p1 = prw[t + 4 + g];
    float2 p2 = prw[t + 8 + g];
    float2 p3 = prw[t + 12 + g];
    int i0 = __float_as_int(p0.y);
    int i1 = __float_as_int(p1.y);
    int i2 = __float_as_int(p2.y);
    int i3 = __float_as_int(p3.y);
    if (BF) {
        uint4 v0 = ((const uint4*)(Xb + (size_t)i0 * 128))[c];
        uint4 v1 = ((const uint4*)(Xb + (size_t)i1 * 128))[c];
        uint4 v2 = ((const uint4*)(Xb + (size_t)i2 * 128))[c];
        uint4 v3 = ((const uint4*)(Xb + (size_t)i3 * 128))[c];
        float b0 = p0.x, b1_ = p1.x, b2_ = p2.x, b3 = p3.x;
        acc[0] += b0 * __uint_as_float(v0.x << 16);
        acc[1] += b0 * __uint_as_float(v0.x & 0xffff0000u);
        acc[2] += b0 * __uint_as_float(v0.y << 16);
        acc[3] += b0 * __uint_as_float(v0.y & 0xffff0000u);
        acc[4] += b0 * __uint_as_float(v0.z << 16);
        acc[5] += b0 * __uint_as_float(v0.z & 0xffff0000u);
        acc[6] += b0 * __uint_as_float(v0.w << 16);
        acc[7] += b0 * __uint_as_float(v0.w & 0xffff0000u);
        acc[0] += b1_ * __uint_as_float(v1.x << 16);
        acc[1] += b1_ * __uint_as_float(v1.x & 0xffff0000u);
        acc[2] += b1_ * __uint_as_float(v1.y << 16);
        acc[3] += b1_ * __uint_as_float(v1.y & 0xffff0000u);
        acc[4] += b1_ * __uint_as_float(v1.z << 16);
        acc[5] += b1_ * __uint_as_float(v1.z & 0xffff0000u);
        acc[6] += b1_ * __uint_as_float(v1.w << 16);
        acc[7] += b1_ * __uint_as_float(v1.w & 0xffff0000u);
        acc[0] += b2_ * __uint_as_float(v2.x << 16);
        acc[1] += b2_ * __uint_as_float(v2.x & 0xffff0000u);
        acc[2] += b2_ * __uint_as_float(v2.y << 16);
        acc[3] += b2_ * __uint_as_float(v2.y & 0xffff0000u);
        acc[4] += b2_ * __uint_as_float(v2.z << 16);
        acc[5] += b2_ * __uint_as_float(v2.z & 0xffff0000u);
        acc[6] += b2_ * __uint_as_float(v2.w << 16);
        acc[7] += b2_ * __uint_as_float(v2.w & 0xffff0000u);
        acc[0] += b3 * __uint_as_float(v3.x << 16);
        acc[1] += b3 * __uint_as_float(v3.x & 0xffff0000u);
        acc[2] += b3 * __uint_as_float(v3.y << 16);
        acc[3] += b3 * __uint_as_float(v3.y & 0xffff0000u);
        acc[4] += b3 * __uint_as_float(v3.z << 16);
        acc[5] += b3 * __uint_as_float(v3.z & 0xffff0000u);
        acc[6] += b3 * __uint_as_float(v3.w << 16);
        acc[7] += b3 * __uint_as_float(v3.w & 0xffff0000u);
    } else {
        const float4* xa = (const float4*)(X + (size_t)i0 * 128 + c * 8);
        const float4* xb = (const float4*)(X + (size_t)i1 * 128 + c * 8);
        const float4* xc = (const float4*)(X + (size_t)i2 * 128 + c * 8);
        const float4* xd = (const float4*)(X + (size_t)i3 * 128 + c * 8);
        float4 a0 = xa[0], a1 = xa[1];
        float4 b0 = xb[0], b1v = xb[1];
        float4 c0 = xc[0], c1 = xc[1];
        float4 d0 = xd[0], d1 = xd[1];
        acc[0] += p0.x * a0.x; acc[1] += p0.x * a0.y;
        acc[2] += p0.x * a0.z; acc[3] += p0.x * a0.w;
        acc[4] += p0.x * a1.x; acc[5] += p0.x * a1.y;
        acc[6] += p0.x * a1.z; acc[7] += p0.x * a1.w;
        acc[0] += p1.x * b0.x; acc[1] += p1.x * b0.y;
        acc[2] += p1.x * b0.z; acc[3] += p1.x * b0.w;
        acc[4] += p1.x * b1v.x; acc[5] += p1.x * b1v.y;
        acc[6] += p1.x * b1v.z; acc[7] += p1.x * b1v.w;
        acc[0] += p2.x * c0.x; acc[1] += p2.x * c0.y;
        acc[2] += p2.x * c0.z; acc[3] += p2.x * c0.w;
        acc[4] += p2.x * c1.x; acc[5] += p2.x * c1.y;
        acc[6] += p2.x * c1.z; acc[7] += p2.x * c1.w;
        acc[0] += p3.x * d0.x; acc[1] += p3.x * d0.y;
        acc[2] += p3.x * d0.z; acc[3] += p3.x * d0.w;
        acc[4] += p3.x * d1.x; acc[5] += p3.x * d1.y;
        acc[6] += p3.x * d1.z; acc[7] += p3.x * d1.w;
    }
}

// ---------------------------------------------------------------------------
// One wave per edge, 4 edges per block. Fast path (n<=64): one sarr gather,
// one expf, butterfly softmax, zero barriers, branch-free 16-row inner loop.
// ---------------------------------------------------------------------------
template <int BF>
__global__ void __launch_bounds__(256) k_edge_agg(
    const float* __restrict__ X, const unsigned short* __restrict__ Xb,
    const float* __restrict__ sarr, const int* __restrict__ node_idx,
    const int* __restrict__ off, float* __restrict__ outZ,
    float* __restrict__ outBeta, int E) {
    int wid = threadIdx.x >> 6, lane = threadIdx.x & 63;
    int e = blockIdx.x * 4 + wid;
    if (e >= E) return;

    __shared__ float2 prs[4][64];   // {beta, bitcast(idx)} per member slot
    float2* prw = prs[wid];

    int s0 = off[e], n = off[e + 1] - s0;
    int g = lane >> 4, c = lane & 15;
    float acc[8] = {0.f, 0.f, 0.f, 0.f, 0.f, 0.f, 0.f, 0.f};

    if (n <= 64) {
        int idxv = 0;
        float svv = -INFINITY;
        if (lane < n) {
            idxv = node_idx[s0 + lane];
            svv = sarr[idxv];
        }
        float m = svv;
#pragma unroll
        for (int d = 1; d < 64; d <<= 1) m = fmaxf(m, __shfl_xor(m, d, 64));
        float ex = (lane < n) ? expf(svv - m) : 0.f;
        float sum = ex;
#pragma unroll
        for (int d = 1; d < 64; d <<= 1) sum += __shfl_xor(sum, d, 64);
        float inv = (n > 0) ? 1.f / sum : 0.f;
        float beta = ex * inv;
        if (lane < n) outBeta[s0 + lane] = beta;
        prw[lane] = make_float2(lane < n ? beta : 0.f,
                                __int_as_float(lane < n ? idxv : 0));
        int nr = (n + 15) & ~15;
        for (int t = 0; t < nr; t += 16)
            row16_acc<BF>(prw, t, g, c, Xb, X, acc);
    } else {
        // rare big-edge fallback (correctness path)
        float m = -INFINITY;
        for (int i = lane; i < n; i += 64)
            m = fmaxf(m, sarr[node_idx[s0 + i]]);
#pragma unroll
        for (int d = 1; d < 64; d <<= 1) m = fmaxf(m, __shfl_xor(m, d, 64));
        float sum = 0.f;
        for (int i = lane; i < n; i += 64)
            sum += expf(sarr[node_idx[s0 + i]] - m);
#pragma unroll
        for (int d = 1; d < 64; d <<= 1) sum += __shfl_xor(sum, d, 64);
        float inv = 1.f / sum;
        for (int base = 0; base < n; base += 64) {
            int cnt = min(64, n - base);
            int idxv = 0;
            float beta = 0.f;
            if (lane < cnt) {
                idxv = node_idx[s0 + base + lane];
                beta = expf(sarr[idxv] - m) * inv;
                outBeta[s0 + base + lane] = beta;
            }
            prw[lane] = make_float2(beta, __int_as_float(idxv));
            int cr = (cnt + 15) & ~15;
            for (int t = 0; t < cr; t += 16)
                row16_acc<BF>(prw, t, g, c, Xb, X, acc);
        }
    }

#pragma unroll
    for (int i = 0; i < 8; ++i) {
        acc[i] += __shfl_xor(acc[i], 16, 64);
        acc[i] += __shfl_xor(acc[i], 32, 64);
    }
    // all 64 lanes: each computes 2 of the 128 outputs (compile-time selects
    // avoid runtime-indexed-array scratch)
    float a0 = acc[0], a1 = acc[1];
    if (g == 1) { a0 = acc[2]; a1 = acc[3]; }
    else if (g == 2) { a0 = acc[4]; a1 = acc[5]; }
    else if (g == 3) { a0 = acc[6]; a1 = acc[7]; }
    float2 o;
    o.x = tanhf(lrelu(a0));
    o.y = tanhf(lrelu(a1));
    *(float2*)(outZ + (size_t)e * 128 + c * 8 + 2 * g) = o;
}

extern "C" void kernel_launch(void* const* d_in, const int* in_sizes, int n_in,
                              void* d_out, int out_size, void* d_ws, size_t ws_size,
                              hipStream_t stream) {
    const float* X  = (const float*)d_in[0];
    const float* W1 = (const float*)d_in[1];
    const float* b1 = (const float*)d_in[2];
    const float* W2 = (const float*)d_in[3];
    const float* b2 = (const float*)d_in[4];
    const int* node_idx = (const int*)d_in[5];
    const int* edge_ids = (const int*)d_in[6];

    int N = in_sizes[0] / 128;          // 100000 nodes
    int M = in_sizes[5];                // 640000 memberships
    int E = (out_size - M) / 128;       // 20000 hyperedges

    // workspace: sarr N f32 | off E+1 ints | Xb N*128 bf16
    char* p = (char*)d_ws;
    float* sarr = (float*)p;
    int*   off  = (int*)(p + (size_t)N * 4);
    size_t xb_off = ((size_t)N * 4 + (size_t)(E + 1) * 4 + 255) & ~(size_t)255;
    unsigned short* Xb = (unsigned short*)(p + xb_off);
    bool useBF = ws_size >= xb_off + (size_t)N * 128 * 2;

    float* outZ    = (float*)d_out;
    float* outBeta = outZ + (size_t)E * 128;

    int NT = (N + 63) / 64;             // 64-node tiles
    int SB = (NT + 1) / 2;              // score blocks: 2 tiles each (~3/CU)
    int OB = (M + 255) / 256;           // offsets blocks
    k_score_and_offsets<<<SB + OB, 256, 0, stream>>>(
        X, W1, b1, W2, b2, sarr, useBF ? Xb : (unsigned short*)nullptr,
        N, SB, NT, edge_ids, off, M, E);
    if (useBF)
        k_edge_agg<1><<<(E + 3) / 4, 256, 0, stream>>>(
            X, Xb, sarr, node_idx, off, outZ, outBeta, E);
    else
        k_edge_agg<0><<<(E + 3) / 4, 256, 0, stream>>>(
            X, Xb, sarr, node_idx, off, outZ, outBeta, E);
}